// Round 1
// 313.254 us; speedup vs baseline: 1.0023x; 1.0023x over previous
//
#include <hip/hip_runtime.h>

#define USER_NUM 1000000
#define EMBED_DIM 64
#define BATCH 16384

// FM second-order term: out[r] = w[u] + w[i] + b + dot(V[u], V[i])
// One wave = 4 rows; 16 lanes/row, each lane loads one float4 of each
// embedding row (16B/lane coalesced), then shfl_xor reduce within the
// 16-lane segment.
//
// vs previous version: w[u], w[i], b[0] are issued EARLY and
// unconditionally (broadcast within the 16-lane segment), so their HBM
// latency overlaps the V-row fetch + shuffle reduce instead of adding a
// serial ~900-cycle round trip after the reduce (loads inside the
// divergent q==0 tail cannot be hoisted by the compiler).
__global__ __launch_bounds__(256, 4) void HE_FM_kernel(
                             const int* __restrict__ inp,
                             const float* __restrict__ w,
                             const float* __restrict__ b,
                             const float* __restrict__ V,
                             float* __restrict__ out) {
    const int gtid = blockIdx.x * blockDim.x + threadIdx.x;
    const int wave = gtid >> 6;          // global wave id
    const int lane = threadIdx.x & 63;
    const int row  = wave * 4 + (lane >> 4);   // 4 rows per wave
    const int q    = lane & 15;                // float4 chunk within row
    if (row >= BATCH) return;

    // both indices in one 8B broadcast load
    const int2 ui = ((const int2*)inp)[row];
    const int u = ui.x;
    const int i = ui.y + USER_NUM;

    // issue scalar gathers first: latency hides under the V fetch + reduce
    const float wu = w[u];
    const float wi = w[i];
    const float bb = b[0];

    const float4 a = ((const float4*)(V + (size_t)u * EMBED_DIM))[q];
    const float4 c = ((const float4*)(V + (size_t)i * EMBED_DIM))[q];

    float dot = a.x * c.x + a.y * c.y + a.z * c.z + a.w * c.w;
    // reduce across the 16 lanes of this row's segment
    dot += __shfl_xor(dot, 8, 16);
    dot += __shfl_xor(dot, 4, 16);
    dot += __shfl_xor(dot, 2, 16);
    dot += __shfl_xor(dot, 1, 16);

    if (q == 0) {
        out[row] = wu + wi + bb + dot;
    }
}

extern "C" void kernel_launch(void* const* d_in, const int* in_sizes, int n_in,
                              void* d_out, int out_size, void* d_ws, size_t ws_size,
                              hipStream_t stream) {
    const int*   inp = (const int*)d_in[0];   // (BATCH, 2) int32
    const float* w   = (const float*)d_in[1]; // (USER_NUM+ITEM_NUM,)
    const float* b   = (const float*)d_in[2]; // (1,)
    const float* V   = (const float*)d_in[3]; // (USER_NUM+ITEM_NUM, EMBED_DIM)
    float*       out = (float*)d_out;         // (BATCH, 1)

    // 4 rows per wave, 4 waves per 256-thread block -> 16 rows/block
    const int rows_per_block = 16;
    const int grid = (BATCH + rows_per_block - 1) / rows_per_block;
    HE_FM_kernel<<<grid, 256, 0, stream>>>(inp, w, b, V, out);
}